// Round 5
// baseline (235.168 us; speedup 1.0000x reference)
//
#include <hip/hip_runtime.h>
#include <hip/hip_cooperative_groups.h>
#include <math.h>

namespace cg = cooperative_groups;

#define PI_F 3.14159265358979323846f
#define BB 2
#define LL 1024
#define NCH 64
#define CHUNK 32
#define NCHUNK (LL/CHUNK)
#define NW 1408          // Wb rows: 512 Wv | 256 Wg1 | 16 Wk | 16 Wq | 96 pad0 | 512 Wo
#define YH 384           // Yh cols: 256 h | 16 kp | 16 qp | 96 pad

typedef __attribute__((ext_vector_type(8))) short short8;
typedef __attribute__((ext_vector_type(4))) float floatx4;
typedef const __attribute__((address_space(1))) unsigned int cgu32;
typedef __attribute__((address_space(3))) unsigned int lu32;

__device__ __forceinline__ unsigned short f2bf(float f){
    unsigned u = __float_as_uint(f);
    unsigned r = (u + 0x7fff + ((u >> 16) & 1)) >> 16;   // RNE
    return (unsigned short)r;
}

// ---- prep: weights -> bf16 Wb[n][k], bcat; x -> bf16 xb ----
__global__ __launch_bounds__(128) void k_prep(
    const float* __restrict__ Wv, const float* __restrict__ Wg1,
    const float* __restrict__ Wk, const float* __restrict__ Wq,
    const float* __restrict__ Wo,
    const float* __restrict__ bv, const float* __restrict__ bg1,
    const float* __restrict__ bk, const float* __restrict__ bq,
    const float* __restrict__ bo, const float* __restrict__ x,
    unsigned short* __restrict__ Wb, float* __restrict__ bcat,
    unsigned short* __restrict__ xb)
{
    const int bid = blockIdx.x, tid = threadIdx.x;
    if (bid < NW){
        const int n = bid;
        const float* src = (n<512) ? Wv  + (size_t)n*512
                         : (n<768) ? Wg1 + (size_t)(n-512)*512
                         : (n<784) ? Wk  + (size_t)(n-768)*512
                         : (n<800) ? Wq  + (size_t)(n-784)*512
                         : (n<896) ? (const float*)0
                                   : Wo  + (size_t)(n-896)*512;
        float4 v = make_float4(0.f,0.f,0.f,0.f);
        if (src) v = ((const float4*)src)[tid];
        ushort4 o; o.x=f2bf(v.x); o.y=f2bf(v.y); o.z=f2bf(v.z); o.w=f2bf(v.w);
        ((ushort4*)(Wb + (size_t)n*512))[tid] = o;
        if (tid == 0)
            bcat[n] = (n<512)?bv[n] : (n<768)?bg1[n-512] : (n<784)?bk[n-768]
                    : (n<800)?bq[n-784] : (n<896)?0.f : bo[n-896];
    } else {
        const size_t i = (size_t)(bid - NW)*128 + tid;    // float4 index
        float4 v = ((const float4*)x)[i];
        ushort4 o; o.x=f2bf(v.x); o.y=f2bf(v.y); o.z=f2bf(v.z); o.w=f2bf(v.w);
        ((ushort4*)xb)[i] = o;
    }
}

// ---- MFMA 128x128x512 tile core: 4 waves, each owns a 64x64 quadrant ----
__device__ __forceinline__ void gemm128(
    const unsigned short* Ag, const unsigned short* Bg,
    short* As, short* Bs, int tid, floatx4 acc[4][4])
{
    const int lane = tid & 63, w = tid >> 6;
    const int wm = w & 1, wn = w >> 1;
    const int q = lane >> 4, m15 = lane & 15;
    for (int kt = 0; kt < 512; kt += 64) {
        __syncthreads();                   // prior iter's frag reads done
        #pragma unroll
        for (int i = 0; i < 4; ++i) {
            const int rowbase = w*32 + i*8;
            const int r  = rowbase + (lane >> 3);
            const int gb = (lane & 7) ^ (r & 7);
            __builtin_amdgcn_global_load_lds(
                (cgu32*)(const void*)(Ag + (size_t)r*512 + kt + gb*8),
                (lu32*)(As + rowbase*64), 16, 0, 0);
            __builtin_amdgcn_global_load_lds(
                (cgu32*)(const void*)(Bg + (size_t)r*512 + kt + gb*8),
                (lu32*)(Bs + rowbase*64), 16, 0, 0);
        }
        __syncthreads();                   // compiler drains vmcnt here
        #pragma unroll
        for (int k32 = 0; k32 < 64; k32 += 32) {
            short8 af[4], bf[4];
            #pragma unroll
            for (int t = 0; t < 4; ++t) {
                const int ra  = 64*wm + 16*t + m15;
                const int sba = ((k32>>3) + q) ^ (ra & 7);
                af[t] = *(const short8*)(As + ra*64 + sba*8);
                const int rb  = 64*wn + 16*t + m15;
                const int sbb = ((k32>>3) + q) ^ (rb & 7);
                bf[t] = *(const short8*)(Bs + rb*64 + sbb*8);
            }
            #pragma unroll
            for (int mt = 0; mt < 4; ++mt)
                #pragma unroll
                for (int nt = 0; nt < 4; ++nt)
                    acc[mt][nt] = __builtin_amdgcn_mfma_f32_16x16x32_bf16(
                        af[mt], bf[nt], acc[mt][nt], 0, 0, 0);
        }
    }
}

// ---- GEMM1: xb @ Wb[0:896]^T; n<512 -> Vt bf16 [b][d][l], n>=512 -> Yh fp32 ----
__global__ __launch_bounds__(256) void kg1(
    const unsigned short* __restrict__ xb, const unsigned short* __restrict__ Wb,
    const float* __restrict__ bcat, unsigned short* __restrict__ Vt,
    float* __restrict__ Yh)
{
    __shared__ short As[128*64], Bs[128*64];
    const int tid = threadIdx.x;
    const int row0 = blockIdx.x*128, n0 = blockIdx.y*128;
    floatx4 acc[4][4];
    #pragma unroll
    for (int mt=0;mt<4;++mt)
        #pragma unroll
        for (int nt=0;nt<4;++nt) acc[mt][nt] = (floatx4){0.f,0.f,0.f,0.f};
    gemm128(xb + (size_t)row0*512, Wb + (size_t)n0*512, As, Bs, tid, acc);
    const int lane = tid & 63, w = tid >> 6;
    const int wm = w & 1, wn = w >> 1, q = lane >> 4, m15 = lane & 15;
    if (n0 < 512){
        const int b = row0 >> 10, lb = row0 & 1023;
        #pragma unroll
        for (int mt=0;mt<4;++mt)
            #pragma unroll
            for (int nt=0;nt<4;++nt){
                const int d = n0 + 64*wn + 16*nt + m15;
                const float bb = bcat[d];
                const int l0 = lb + 64*wm + 16*mt + q*4;
                ushort4 o;
                o.x = f2bf(acc[mt][nt][0] + bb);
                o.y = f2bf(acc[mt][nt][1] + bb);
                o.z = f2bf(acc[mt][nt][2] + bb);
                o.w = f2bf(acc[mt][nt][3] + bb);
                *(ushort4*)(Vt + ((size_t)(b*512 + d))*1024 + l0) = o;
            }
    } else {
        #pragma unroll
        for (int mt=0;mt<4;++mt)
            #pragma unroll
            for (int nt=0;nt<4;++nt){
                const int n = n0 + 64*wn + 16*nt + m15;
                const float bb = bcat[n];
                #pragma unroll
                for (int reg=0;reg<4;++reg){
                    const int m = row0 + 64*wm + 16*mt + q*4 + reg;
                    Yh[(size_t)m*YH + (n-512)] = acc[mt][nt][reg] + bb;
                }
            }
    }
}

// ---- cooperative scan kernel: act | chunk-sums | prefix | intra+LN ----
__global__ __launch_bounds__(256) void k_scan(
    const float* __restrict__ Yh, const float* __restrict__ Wg2,
    const float* __restrict__ bg2, const float* __restrict__ set_w,
    const float* __restrict__ pos_phases, const float* __restrict__ pos_weight,
    const unsigned short* __restrict__ Vt,
    unsigned short* __restrict__ ab, unsigned short* __restrict__ Rb,
    unsigned short* __restrict__ aT, float* __restrict__ P,
    unsigned short* __restrict__ S0t,
    const float* __restrict__ ln_g, const float* __restrict__ ln_b,
    unsigned short* __restrict__ Tn)
{
    __shared__ float Tsh[32*512];        // 64 KB (stage D)
    __shared__ short Msh[32*32];         // 2 KB  (stage D)
    cg::grid_group grid = cg::this_grid();
    const int bid = blockIdx.x, tid = threadIdx.x;
    const int lane = tid & 63, w = tid >> 6;
    const int q = lane >> 4, m15 = lane & 15;

    // ---- stage A: activations (16 rows per block) ----
    {
        const int row0 = bid * 16;
        float s0=set_w[0], s1=set_w[1], s2=set_w[2], s3=set_w[3];
        float m = fmaxf(fmaxf(s0,s1), fmaxf(s2,s3));
        float e0=expf(s0-m), e1=expf(s1-m), e2=expf(s2-m), e3=expf(s3-m);
        float esum = e0+e1+e2+e3;
        float spw = 1.f/(1.f+expf(-pos_weight[0]));
        float b2 = bg2[0];
        #pragma unroll
        for (int rr=0;rr<4;++rr){
            int row = row0 + w + 4*rr;
            const float* yrow = Yh + (size_t)row*YH;
            float hs = 0.f;
            #pragma unroll
            for (int i=0;i<4;++i){
                float hv = yrow[lane + 64*i];
                float ge = 0.5f*hv*(1.f + erff(hv*0.70710678118f));
                hs += ge * Wg2[lane + 64*i];
            }
            #pragma unroll
            for (int off=32; off; off>>=1) hs += __shfl_xor(hs, off, 64);
            float g = 1.f/(1.f+expf(-(hs + b2)));
            if (lane < 16){
                int j = lane;
                int l = row & (LL-1);
                int b = row >> 10;
                float kang = PI_F*tanhf(yrow[256 + j]);
                float qang = PI_F*tanhf(yrow[272 + j]);
                float wsm = (j<4?e0: j<8?e1: j<12?e2: e3) / esum;
                float rnorm = 1.f/(2.f*sqrtf((float)(l+1)));
                float av[4], rv[4];
                av[0] = cosf(kang); av[1] = sinf(kang);
                float cw = g*wsm*rnorm;
                rv[0] = cw*cosf(qang); rv[1] = cw*sinf(qang);
                float ph = pos_phases[(size_t)l*16 + j];
                float pc = cosf(ph), ps = sinf(ph);
                av[2] = pc; av[3] = ps;
                float cp = (1.f-g)*spw*rnorm;
                rv[2] = cp*pc; rv[3] = cp*ps;
                unsigned short* arow = ab + (size_t)row*NCH;
                unsigned short* Rrow = Rb + (size_t)row*NCH;
                #pragma unroll
                for (int t=0;t<4;++t){
                    arow[16*t + j] = f2bf(av[t]);
                    Rrow[16*t + j] = f2bf(rv[t]);
                    aT[((size_t)b*NCH + 16*t + j)*1024 + l] = f2bf(av[t]);
                }
            }
        }
    }
    grid.sync();

    // ---- stage B: per-chunk sums P[b][c][d][k] (MFMA) ----
    {
        const int c = bid & 31, b = (bid >> 5) & 1, z = bid >> 6;
        short8 af[4];
        #pragma unroll
        for (int mt=0;mt<4;++mt)
            af[mt] = *(const short8*)(aT + ((size_t)b*NCH + 16*mt + m15)*1024 + c*32 + q*8);
        floatx4 acc[4][4];
        #pragma unroll
        for (int mt=0;mt<4;++mt)
            #pragma unroll
            for (int nt=0;nt<4;++nt) acc[mt][nt] = (floatx4){0.f,0.f,0.f,0.f};
        #pragma unroll
        for (int nt=0;nt<4;++nt){
            const int d = z*256 + w*64 + 16*nt + m15;
            short8 bf = *(const short8*)(Vt + ((size_t)(b*512 + d))*1024 + c*32 + q*8);
            #pragma unroll
            for (int mt=0;mt<4;++mt)
                acc[mt][nt] = __builtin_amdgcn_mfma_f32_16x16x32_bf16(af[mt], bf, acc[mt][nt], 0,0,0);
        }
        float* Pc = P + ((size_t)(b*NCHUNK + c))*512*NCH;
        #pragma unroll
        for (int mt=0;mt<4;++mt)
            #pragma unroll
            for (int nt=0;nt<4;++nt){
                const int d = z*256 + w*64 + 16*nt + m15;
                *(floatx4*)(Pc + (size_t)d*NCH + 16*mt + q*4) = acc[mt][nt];
            }
    }
    grid.sync();

    // ---- stage C: exclusive prefix over chunks -> S0t bf16 ----
    {
        const size_t idx = (size_t)bid*256 + tid;          // over 512*64
        #pragma unroll
        for (int b=0;b<BB;++b){
            float run = 0.f;
            for (int c=0;c<NCHUNK;++c){
                const size_t o = ((size_t)(b*NCHUNK + c))*512*NCH + idx;
                float v = P[o];
                S0t[o] = f2bf(run);
                run += v;
            }
        }
    }
    grid.sync();

    // ---- stage D: T = tril(R a^T) @ V + R @ S0, then LN -> Tn (64 blocks) ----
    if (bid < 64){
        const int c = bid & 31, b = bid >> 5;
        const int grow = b*1024 + c*32;

        if (w == 0){                       // wave 0 computes M = tril(R @ a^T)
            floatx4 mcc[2][2];
            #pragma unroll
            for (int mt=0;mt<2;++mt)
                #pragma unroll
                for (int nt=0;nt<2;++nt) mcc[mt][nt] = (floatx4){0.f,0.f,0.f,0.f};
            #pragma unroll
            for (int ks=0;ks<2;++ks){
                short8 ra[2], bb[2];
                #pragma unroll
                for (int t=0;t<2;++t){
                    ra[t] = *(const short8*)(Rb + (size_t)(grow + 16*t + m15)*NCH + ks*32 + q*8);
                    bb[t] = *(const short8*)(ab + (size_t)(grow + 16*t + m15)*NCH + ks*32 + q*8);
                }
                #pragma unroll
                for (int mt=0;mt<2;++mt)
                    #pragma unroll
                    for (int nt=0;nt<2;++nt)
                        mcc[mt][nt] = __builtin_amdgcn_mfma_f32_16x16x32_bf16(
                            ra[mt], bb[nt], mcc[mt][nt], 0,0,0);
            }
            #pragma unroll
            for (int mt=0;mt<2;++mt)
                #pragma unroll
                for (int nt=0;nt<2;++nt){
                    const int nl = 16*nt + m15;
                    #pragma unroll
                    for (int reg=0;reg<4;++reg){
                        const int ml = 16*mt + q*4 + reg;
                        Msh[ml*32 + nl] = (nl <= ml) ? (short)f2bf(mcc[mt][nt][reg]) : (short)0;
                    }
                }
        }
        __syncthreads();

        short8 a1[2], a2[2][2];
        #pragma unroll
        for (int mt=0;mt<2;++mt){
            a1[mt] = *(const short8*)(Msh + (16*mt + m15)*32 + q*8);
            #pragma unroll
            for (int ks=0;ks<2;++ks)
                a2[ks][mt] = *(const short8*)(Rb + (size_t)(grow + 16*mt + m15)*NCH + ks*32 + q*8);
        }
        floatx4 acc[2][8];
        #pragma unroll
        for (int mt=0;mt<2;++mt)
            #pragma unroll
            for (int nt=0;nt<8;++nt) acc[mt][nt] = (floatx4){0.f,0.f,0.f,0.f};
        const unsigned short* S0c = S0t + ((size_t)(b*NCHUNK + c))*512*NCH;
        #pragma unroll
        for (int nt=0;nt<8;++nt){
            const int d = w*128 + 16*nt + m15;
            short8 b1 = *(const short8*)(Vt + ((size_t)(b*512 + d))*1024 + c*32 + q*8);
            #pragma unroll
            for (int mt=0;mt<2;++mt)
                acc[mt][nt] = __builtin_amdgcn_mfma_f32_16x16x32_bf16(a1[mt], b1, acc[mt][nt], 0,0,0);
            #pragma unroll
            for (int ks=0;ks<2;++ks){
                short8 b2 = *(const short8*)(S0c + (size_t)d*NCH + ks*32 + q*8);
                #pragma unroll
                for (int mt=0;mt<2;++mt)
                    acc[mt][nt] = __builtin_amdgcn_mfma_f32_16x16x32_bf16(a2[ks][mt], b2, acc[mt][nt], 0,0,0);
            }
        }
        #pragma unroll
        for (int mt=0;mt<2;++mt)
            #pragma unroll
            for (int nt=0;nt<8;++nt){
                const int d = w*128 + 16*nt + m15;
                #pragma unroll
                for (int reg=0;reg<4;++reg)
                    Tsh[(16*mt + q*4 + reg)*512 + d] = acc[mt][nt][reg];
            }
        __syncthreads();

        #pragma unroll
        for (int i=0;i<8;++i){
            const int r = w*8 + i;
            float s=0.f, sq=0.f;
            #pragma unroll
            for (int t=0;t<8;++t){
                float v = Tsh[r*512 + lane + 64*t];
                s += v; sq += v*v;
            }
            #pragma unroll
            for (int off=32; off; off>>=1){
                s += __shfl_xor(s, off, 64); sq += __shfl_xor(sq, off, 64);
            }
            float mu  = s*(1.f/512.f);
            float var = sq*(1.f/512.f) - mu*mu;
            float rsd = rsqrtf(var + 1e-5f);
            unsigned short* trow = Tn + (size_t)(grow + r)*512;
            #pragma unroll
            for (int t=0;t<8;++t){
                const int d = lane + 64*t;
                float v = (Tsh[r*512 + d] - mu)*rsd*ln_g[d] + ln_b[d];
                trow[d] = f2bf(v);
            }
        }
    }
}

// ---- GEMM2: out = x + Tn @ Wo^T + bo ----
__global__ __launch_bounds__(256) void kg2(
    const unsigned short* __restrict__ Tn, const unsigned short* __restrict__ Wb,
    const float* __restrict__ bcat, const float* __restrict__ x,
    float* __restrict__ out)
{
    __shared__ short As[128*64], Bs[128*64];
    const int tid = threadIdx.x;
    const int row0 = blockIdx.x*128, n0 = blockIdx.y*128;
    floatx4 acc[4][4];
    #pragma unroll
    for (int mt=0;mt<4;++mt)
        #pragma unroll
        for (int nt=0;nt<4;++nt) acc[mt][nt] = (floatx4){0.f,0.f,0.f,0.f};
    gemm128(Tn + (size_t)row0*512, Wb + (size_t)(896+n0)*512, As, Bs, tid, acc);
    const int lane = tid & 63, w = tid >> 6;
    const int wm = w & 1, wn = w >> 1, q = lane >> 4, m15 = lane & 15;
    #pragma unroll
    for (int mt=0;mt<4;++mt)
        #pragma unroll
        for (int nt=0;nt<4;++nt){
            const int n = n0 + 64*wn + 16*nt + m15;
            const float bb = bcat[896 + n];
            #pragma unroll
            for (int reg=0;reg<4;++reg){
                const int m = row0 + 64*wm + 16*mt + q*4 + reg;
                out[(size_t)m*512 + n] = x[(size_t)m*512 + n] + acc[mt][nt][reg] + bb;
            }
        }
}

extern "C" void kernel_launch(void* const* d_in, const int* in_sizes, int n_in,
                              void* d_out, int out_size, void* d_ws, size_t ws_size,
                              hipStream_t stream) {
    const float* x    = (const float*)d_in[0];
    const float* Wk   = (const float*)d_in[1];
    const float* bk   = (const float*)d_in[2];
    const float* Wq   = (const float*)d_in[3];
    const float* bq   = (const float*)d_in[4];
    const float* Wv   = (const float*)d_in[5];
    const float* bv   = (const float*)d_in[6];
    const float* ln_g = (const float*)d_in[7];
    const float* ln_b = (const float*)d_in[8];
    const float* Wo   = (const float*)d_in[9];
    const float* bo   = (const float*)d_in[10];
    const float* set_w      = (const float*)d_in[11];
    const float* pos_phases = (const float*)d_in[12];
    const float* pos_weight = (const float*)d_in[13];
    const float* Wg1  = (const float*)d_in[14];
    const float* bg1  = (const float*)d_in[15];
    const float* Wg2  = (const float*)d_in[16];
    const float* bg2  = (const float*)d_in[17];
    float* out = (float*)d_out;

    // workspace: fp32 region, then bf16 region (~24 MB)
    float* ws   = (float*)d_ws;
    float* Yh   = ws;                                     // 2048*384
    float* P    = Yh + (size_t)2048*YH;                   // 2*32*512*64
    float* bcat = P  + (size_t)BB*NCHUNK*512*NCH;         // 1408
    unsigned short* Wb  = (unsigned short*)(bcat + NW);   // 1408*512
    unsigned short* xb  = Wb  + (size_t)NW*512;           // 2048*512
    unsigned short* Vt  = xb  + (size_t)2048*512;         // 2*512*1024
    unsigned short* ab  = Vt  + (size_t)BB*512*1024;      // 2048*64
    unsigned short* Rb  = ab  + (size_t)2048*NCH;         // 2048*64
    unsigned short* aT  = Rb  + (size_t)2048*NCH;         // 2*64*1024
    unsigned short* S0t = aT  + (size_t)BB*NCH*1024;      // 2*32*512*64
    unsigned short* Tn  = S0t + (size_t)BB*NCHUNK*512*NCH;// 2048*512

    k_prep<<<dim3(NW + 2048), 128, 0, stream>>>(
        Wv,Wg1,Wk,Wq,Wo, bv,bg1,bk,bq,bo, x, Wb, bcat, xb);
    kg1<<<dim3(2048/128, 7), 256, 0, stream>>>(xb, Wb, bcat, Vt, Yh);
    {
        void* args[] = {
            (void*)&Yh, (void*)&Wg2, (void*)&bg2, (void*)&set_w,
            (void*)&pos_phases, (void*)&pos_weight, (void*)&Vt,
            (void*)&ab, (void*)&Rb, (void*)&aT, (void*)&P, (void*)&S0t,
            (void*)&ln_g, (void*)&ln_b, (void*)&Tn
        };
        hipLaunchCooperativeKernel((const void*)k_scan, dim3(128), dim3(256),
                                   args, 0, stream);
    }
    kg2<<<dim3(2048/128, 4), 256, 0, stream>>>(Tn, Wb, bcat, x, out);
}

// Round 6
// 213.236 us; speedup vs baseline: 1.1028x; 1.1028x over previous
//
#include <hip/hip_runtime.h>
#include <math.h>

#define PI_F 3.14159265358979323846f
#define BB 2
#define LL 1024
#define NCH 64
#define CHUNK 32
#define NCHUNK (LL/CHUNK)
#define NW 1408          // Wb rows: 512 Wv | 256 Wg1 | 16 Wk | 16 Wq | 96 pad0 | 512 Wo
#define YH 384           // Yh cols: 256 h | 16 kp | 16 qp | 96 pad

typedef __attribute__((ext_vector_type(8))) short short8;
typedef __attribute__((ext_vector_type(4))) float floatx4;
typedef const __attribute__((address_space(1))) unsigned int cgu32;
typedef __attribute__((address_space(3))) unsigned int lu32;

__device__ __forceinline__ unsigned short f2bf(float f){
    unsigned u = __float_as_uint(f);
    unsigned r = (u + 0x7fff + ((u >> 16) & 1)) >> 16;   // RNE
    return (unsigned short)r;
}
__device__ __forceinline__ float bf2f(unsigned short u){
    return __uint_as_float(((unsigned)u) << 16);
}

// ---- prep: weights -> bf16 Wb[n][k], bcat; x -> bf16 xb ----
__global__ __launch_bounds__(128) void k_prep(
    const float* __restrict__ Wv, const float* __restrict__ Wg1,
    const float* __restrict__ Wk, const float* __restrict__ Wq,
    const float* __restrict__ Wo,
    const float* __restrict__ bv, const float* __restrict__ bg1,
    const float* __restrict__ bk, const float* __restrict__ bq,
    const float* __restrict__ bo, const float* __restrict__ x,
    unsigned short* __restrict__ Wb, float* __restrict__ bcat,
    unsigned short* __restrict__ xb)
{
    const int bid = blockIdx.x, tid = threadIdx.x;
    if (bid < NW){
        const int n = bid;
        const float* src = (n<512) ? Wv  + (size_t)n*512
                         : (n<768) ? Wg1 + (size_t)(n-512)*512
                         : (n<784) ? Wk  + (size_t)(n-768)*512
                         : (n<800) ? Wq  + (size_t)(n-784)*512
                         : (n<896) ? (const float*)0
                                   : Wo  + (size_t)(n-896)*512;
        float4 v = make_float4(0.f,0.f,0.f,0.f);
        if (src) v = ((const float4*)src)[tid];
        ushort4 o; o.x=f2bf(v.x); o.y=f2bf(v.y); o.z=f2bf(v.z); o.w=f2bf(v.w);
        ((ushort4*)(Wb + (size_t)n*512))[tid] = o;
        if (tid == 0)
            bcat[n] = (n<512)?bv[n] : (n<768)?bg1[n-512] : (n<784)?bk[n-768]
                    : (n<800)?bq[n-784] : (n<896)?0.f : bo[n-896];
    } else {
        const size_t i = (size_t)(bid - NW)*128 + tid;    // float4 index
        float4 v = ((const float4*)x)[i];
        ushort4 o; o.x=f2bf(v.x); o.y=f2bf(v.y); o.z=f2bf(v.z); o.w=f2bf(v.w);
        ((ushort4*)xb)[i] = o;
    }
}

// ---- MFMA 128x128x512 tile core: 4 waves, each owns a 64x64 quadrant ----
__device__ __forceinline__ void gemm128(
    const unsigned short* Ag, const unsigned short* Bg,
    short* As, short* Bs, int tid, floatx4 acc[4][4])
{
    const int lane = tid & 63, w = tid >> 6;
    const int wm = w & 1, wn = w >> 1;
    const int q = lane >> 4, m15 = lane & 15;
    for (int kt = 0; kt < 512; kt += 64) {
        __syncthreads();                   // prior iter's frag reads done
        #pragma unroll
        for (int i = 0; i < 4; ++i) {
            const int rowbase = w*32 + i*8;
            const int r  = rowbase + (lane >> 3);
            const int gb = (lane & 7) ^ (r & 7);
            __builtin_amdgcn_global_load_lds(
                (cgu32*)(const void*)(Ag + (size_t)r*512 + kt + gb*8),
                (lu32*)(As + rowbase*64), 16, 0, 0);
            __builtin_amdgcn_global_load_lds(
                (cgu32*)(const void*)(Bg + (size_t)r*512 + kt + gb*8),
                (lu32*)(Bs + rowbase*64), 16, 0, 0);
        }
        __syncthreads();                   // compiler drains vmcnt here
        #pragma unroll
        for (int k32 = 0; k32 < 64; k32 += 32) {
            short8 af[4], bf[4];
            #pragma unroll
            for (int t = 0; t < 4; ++t) {
                const int ra  = 64*wm + 16*t + m15;
                const int sba = ((k32>>3) + q) ^ (ra & 7);
                af[t] = *(const short8*)(As + ra*64 + sba*8);
                const int rb  = 64*wn + 16*t + m15;
                const int sbb = ((k32>>3) + q) ^ (rb & 7);
                bf[t] = *(const short8*)(Bs + rb*64 + sbb*8);
            }
            #pragma unroll
            for (int mt = 0; mt < 4; ++mt)
                #pragma unroll
                for (int nt = 0; nt < 4; ++nt)
                    acc[mt][nt] = __builtin_amdgcn_mfma_f32_16x16x32_bf16(
                        af[mt], bf[nt], acc[mt][nt], 0, 0, 0);
        }
    }
}

// ---- GEMM1: xb @ Wb[0:896]^T; n<512 -> Vt bf16 [b][d][l], n>=512 -> Yh fp32 ----
__global__ __launch_bounds__(256) void kg1(
    const unsigned short* __restrict__ xb, const unsigned short* __restrict__ Wb,
    const float* __restrict__ bcat, unsigned short* __restrict__ Vt,
    float* __restrict__ Yh)
{
    __shared__ short As[128*64], Bs[128*64];
    const int tid = threadIdx.x;
    const int row0 = blockIdx.x*128, n0 = blockIdx.y*128;
    floatx4 acc[4][4];
    #pragma unroll
    for (int mt=0;mt<4;++mt)
        #pragma unroll
        for (int nt=0;nt<4;++nt) acc[mt][nt] = (floatx4){0.f,0.f,0.f,0.f};
    gemm128(xb + (size_t)row0*512, Wb + (size_t)n0*512, As, Bs, tid, acc);
    const int lane = tid & 63, w = tid >> 6;
    const int wm = w & 1, wn = w >> 1, q = lane >> 4, m15 = lane & 15;
    if (n0 < 512){
        const int b = row0 >> 10, lb = row0 & 1023;
        #pragma unroll
        for (int mt=0;mt<4;++mt)
            #pragma unroll
            for (int nt=0;nt<4;++nt){
                const int d = n0 + 64*wn + 16*nt + m15;
                const float bb = bcat[d];
                const int l0 = lb + 64*wm + 16*mt + q*4;
                ushort4 o;
                o.x = f2bf(acc[mt][nt][0] + bb);
                o.y = f2bf(acc[mt][nt][1] + bb);
                o.z = f2bf(acc[mt][nt][2] + bb);
                o.w = f2bf(acc[mt][nt][3] + bb);
                *(ushort4*)(Vt + ((size_t)(b*512 + d))*1024 + l0) = o;
            }
    } else {
        #pragma unroll
        for (int mt=0;mt<4;++mt)
            #pragma unroll
            for (int nt=0;nt<4;++nt){
                const int n = n0 + 64*wn + 16*nt + m15;
                const float bb = bcat[n];
                #pragma unroll
                for (int reg=0;reg<4;++reg){
                    const int m = row0 + 64*wm + 16*mt + q*4 + reg;
                    Yh[(size_t)m*YH + (n-512)] = acc[mt][nt][reg] + bb;
                }
            }
    }
}

// ---- activations -> bf16 ab[l][64], Rb[l][64], aT[b][k][l] ----
__global__ __launch_bounds__(256) void k_act(
    const float* __restrict__ Yh, const float* __restrict__ Wg2,
    const float* __restrict__ bg2, const float* __restrict__ set_w,
    const float* __restrict__ pos_phases, const float* __restrict__ pos_weight,
    unsigned short* __restrict__ ab, unsigned short* __restrict__ Rb,
    unsigned short* __restrict__ aT)
{
    const int tid = threadIdx.x, lane = tid & 63, w = tid >> 6;
    const int row0 = blockIdx.x * 8;
    float s0=set_w[0], s1=set_w[1], s2=set_w[2], s3=set_w[3];
    float m = fmaxf(fmaxf(s0,s1), fmaxf(s2,s3));
    float e0=expf(s0-m), e1=expf(s1-m), e2=expf(s2-m), e3=expf(s3-m);
    float esum = e0+e1+e2+e3;
    float spw = 1.f/(1.f+expf(-pos_weight[0]));
    float b2 = bg2[0];
    #pragma unroll
    for (int rr=0;rr<2;++rr){
        int row = row0 + w + 4*rr;
        const float* yrow = Yh + (size_t)row*YH;
        float hs = 0.f;
        #pragma unroll
        for (int i=0;i<4;++i){
            float hv = yrow[lane + 64*i];
            float ge = 0.5f*hv*(1.f + erff(hv*0.70710678118f));
            hs += ge * Wg2[lane + 64*i];
        }
        #pragma unroll
        for (int off=32; off; off>>=1) hs += __shfl_xor(hs, off, 64);
        float g = 1.f/(1.f+expf(-(hs + b2)));
        if (lane < 16){
            int j = lane;
            int l = row & (LL-1);
            int b = row >> 10;
            float kang = PI_F*tanhf(yrow[256 + j]);
            float qang = PI_F*tanhf(yrow[272 + j]);
            float wsm = (j<4?e0: j<8?e1: j<12?e2: e3) / esum;
            float rnorm = 1.f/(2.f*sqrtf((float)(l+1)));
            float av[4], rv[4];
            av[0] = cosf(kang); av[1] = sinf(kang);
            float cw = g*wsm*rnorm;
            rv[0] = cw*cosf(qang); rv[1] = cw*sinf(qang);
            float ph = pos_phases[(size_t)l*16 + j];
            float pc = cosf(ph), ps = sinf(ph);
            av[2] = pc; av[3] = ps;
            float cp = (1.f-g)*spw*rnorm;
            rv[2] = cp*pc; rv[3] = cp*ps;
            unsigned short* arow = ab + (size_t)row*NCH;
            unsigned short* Rrow = Rb + (size_t)row*NCH;
            #pragma unroll
            for (int t=0;t<4;++t){
                arow[16*t + j] = f2bf(av[t]);
                Rrow[16*t + j] = f2bf(rv[t]);
                aT[((size_t)b*NCH + 16*t + j)*1024 + l] = f2bf(av[t]);
            }
        }
    }
}

// ---- k_scan2: fused chunk-scan. 1 wave per block, block owns (b, 32-wide
// d-slice); full 64-ch state S for that slice lives in LDS (fp32 + bf16
// mirror). Zero barriers: wave-private S, wave-private M copy, same-wave
// LDS RAW handled by lgkmcnt. Per chunk: M=tril(R a^T) | T = M@V + R@S_bf |
// S += a^T@V. Writes un-normalized T (bf16); k_ln normalizes after. ----
__global__ __launch_bounds__(64) void k_scan2(
    const unsigned short* __restrict__ ab, const unsigned short* __restrict__ Rb,
    const unsigned short* __restrict__ aT, const unsigned short* __restrict__ Vt,
    unsigned short* __restrict__ Tn)
{
    __shared__ float S_f[NCH*32];       // [ch][d_local]  8 KB
    __shared__ short S_bf[32*NCH];      // [d_local][ch]  4 KB
    __shared__ short M_bf[32*32];       // tril(R a^T)    2 KB
    const int tid = threadIdx.x;
    const int q = tid >> 4, m15 = tid & 15;
    const int b = blockIdx.x >> 4, d0 = (blockIdx.x & 15) * 32;

    // zero state
    for (int i = tid; i < NCH*32; i += 64) S_f[i] = 0.f;
    for (int i = tid; i < 32*NCH; i += 64) S_bf[i] = 0;
    // no barrier needed: single wave

    for (int c = 0; c < NCHUNK; ++c){
        const int grow = b*1024 + c*32;

        // ---- step 1: M = tril(R @ a^T) (32x32, k=64) ----
        short8 ra[2][2], bb[2][2];
        #pragma unroll
        for (int ks=0;ks<2;++ks)
            #pragma unroll
            for (int t=0;t<2;++t){
                ra[ks][t] = *(const short8*)(Rb + (size_t)(grow + 16*t + m15)*NCH + ks*32 + q*8);
                bb[ks][t] = *(const short8*)(ab + (size_t)(grow + 16*t + m15)*NCH + ks*32 + q*8);
            }
        floatx4 mcc[2][2];
        #pragma unroll
        for (int mt=0;mt<2;++mt)
            #pragma unroll
            for (int nt=0;nt<2;++nt) mcc[mt][nt] = (floatx4){0.f,0.f,0.f,0.f};
        #pragma unroll
        for (int ks=0;ks<2;++ks)
            #pragma unroll
            for (int mt=0;mt<2;++mt)
                #pragma unroll
                for (int nt=0;nt<2;++nt)
                    mcc[mt][nt] = __builtin_amdgcn_mfma_f32_16x16x32_bf16(
                        ra[ks][mt], bb[ks][nt], mcc[mt][nt], 0,0,0);
        #pragma unroll
        for (int mt=0;mt<2;++mt)
            #pragma unroll
            for (int nt=0;nt<2;++nt){
                const int nl = 16*nt + m15;
                #pragma unroll
                for (int reg=0;reg<4;++reg){
                    const int ml = 16*mt + q*4 + reg;
                    M_bf[ml*32 + nl] = (nl <= ml) ? (short)f2bf(mcc[mt][nt][reg]) : (short)0;
                }
            }

        // ---- step 2+3: T = M@V + R@S_bf  (32 rows x 32 d) ----
        short8 a1[2], vfr[2];
        #pragma unroll
        for (int mt=0;mt<2;++mt)
            a1[mt] = *(const short8*)(M_bf + (16*mt + m15)*32 + q*8);
        #pragma unroll
        for (int nt=0;nt<2;++nt)
            vfr[nt] = *(const short8*)(Vt + ((size_t)(b*512 + d0 + 16*nt + m15))*1024 + c*32 + q*8);
        floatx4 tac[2][2];
        #pragma unroll
        for (int mt=0;mt<2;++mt)
            #pragma unroll
            for (int nt=0;nt<2;++nt) tac[mt][nt] = (floatx4){0.f,0.f,0.f,0.f};
        #pragma unroll
        for (int mt=0;mt<2;++mt)
            #pragma unroll
            for (int nt=0;nt<2;++nt)
                tac[mt][nt] = __builtin_amdgcn_mfma_f32_16x16x32_bf16(
                    a1[mt], vfr[nt], tac[mt][nt], 0,0,0);
        #pragma unroll
        for (int ks=0;ks<2;++ks){
            short8 sfr[2];
            #pragma unroll
            for (int nt=0;nt<2;++nt)
                sfr[nt] = *(const short8*)(S_bf + (16*nt + m15)*NCH + ks*32 + q*8);
            #pragma unroll
            for (int mt=0;mt<2;++mt)
                #pragma unroll
                for (int nt=0;nt<2;++nt)
                    tac[mt][nt] = __builtin_amdgcn_mfma_f32_16x16x32_bf16(
                        ra[ks][mt], sfr[nt], tac[mt][nt], 0,0,0);
        }
        // write T (un-normalized) bf16
        #pragma unroll
        for (int mt=0;mt<2;++mt)
            #pragma unroll
            for (int nt=0;nt<2;++nt){
                const int d = d0 + 16*nt + m15;
                #pragma unroll
                for (int reg=0;reg<4;++reg){
                    const int row = grow + 16*mt + q*4 + reg;
                    Tn[(size_t)row*512 + d] = f2bf(tac[mt][nt][reg]);
                }
            }

        // ---- step 4: S += a^T @ V  (64 ch x 32 d, k=32) ----
        #pragma unroll
        for (int mtc=0;mtc<4;++mtc){
            short8 atf = *(const short8*)(aT + ((size_t)(b*NCH + 16*mtc + m15))*1024 + c*32 + q*8);
            #pragma unroll
            for (int nt=0;nt<2;++nt){
                floatx4 cfr;
                const int dl = 16*nt + m15;
                #pragma unroll
                for (int reg=0;reg<4;++reg)
                    cfr[reg] = S_f[(16*mtc + q*4 + reg)*32 + dl];
                cfr = __builtin_amdgcn_mfma_f32_16x16x32_bf16(atf, vfr[nt], cfr, 0,0,0);
                ushort4 sb;
                #pragma unroll
                for (int reg=0;reg<4;++reg){
                    S_f[(16*mtc + q*4 + reg)*32 + dl] = cfr[reg];
                    ((unsigned short*)&sb)[reg] = f2bf(cfr[reg]);
                }
                *(ushort4*)(S_bf + dl*NCH + 16*mtc + q*4) = sb;
            }
        }
    }
}

// ---- k_ln: LayerNorm rows of Tn (bf16) in place ----
__global__ __launch_bounds__(256) void k_ln(
    unsigned short* __restrict__ Tn, const float* __restrict__ ln_g,
    const float* __restrict__ ln_b)
{
    const int tid = threadIdx.x, lane = tid & 63;
    const int r = blockIdx.x*4 + (tid >> 6);
    ushort4* trow = (ushort4*)(Tn + (size_t)r*512);
    ushort4 u0 = trow[lane], u1 = trow[lane+64];
    float v[8] = { bf2f(u0.x), bf2f(u0.y), bf2f(u0.z), bf2f(u0.w),
                   bf2f(u1.x), bf2f(u1.y), bf2f(u1.z), bf2f(u1.w) };
    float s=0.f, sq=0.f;
    #pragma unroll
    for (int i=0;i<8;++i){ s += v[i]; sq += v[i]*v[i]; }
    #pragma unroll
    for (int off=32; off; off>>=1){
        s += __shfl_xor(s, off, 64); sq += __shfl_xor(sq, off, 64);
    }
    float mu  = s*(1.f/512.f);
    float var = sq*(1.f/512.f) - mu*mu;
    float rsd = rsqrtf(var + 1e-5f);
    float4 g0 = ((const float4*)ln_g)[lane], g1 = ((const float4*)ln_g)[lane+64];
    float4 b0 = ((const float4*)ln_b)[lane], b1 = ((const float4*)ln_b)[lane+64];
    ushort4 o0, o1;
    o0.x = f2bf((v[0]-mu)*rsd*g0.x + b0.x);
    o0.y = f2bf((v[1]-mu)*rsd*g0.y + b0.y);
    o0.z = f2bf((v[2]-mu)*rsd*g0.z + b0.z);
    o0.w = f2bf((v[3]-mu)*rsd*g0.w + b0.w);
    o1.x = f2bf((v[4]-mu)*rsd*g1.x + b1.x);
    o1.y = f2bf((v[5]-mu)*rsd*g1.y + b1.y);
    o1.z = f2bf((v[6]-mu)*rsd*g1.z + b1.z);
    o1.w = f2bf((v[7]-mu)*rsd*g1.w + b1.w);
    trow[lane] = o0; trow[lane+64] = o1;
}

// ---- GEMM2: out = x + Tn @ Wo^T + bo ----
__global__ __launch_bounds__(256) void kg2(
    const unsigned short* __restrict__ Tn, const unsigned short* __restrict__ Wb,
    const float* __restrict__ bcat, const float* __restrict__ x,
    float* __restrict__ out)
{
    __shared__ short As[128*64], Bs[128*64];
    const int tid = threadIdx.x;
    const int row0 = blockIdx.x*128, n0 = blockIdx.y*128;
    floatx4 acc[4][4];
    #pragma unroll
    for (int mt=0;mt<4;++mt)
        #pragma unroll
        for (int nt=0;nt<4;++nt) acc[mt][nt] = (floatx4){0.f,0.f,0.f,0.f};
    gemm128(Tn + (size_t)row0*512, Wb + (size_t)(896+n0)*512, As, Bs, tid, acc);
    const int lane = tid & 63, w = tid >> 6;
    const int wm = w & 1, wn = w >> 1, q = lane >> 4, m15 = lane & 15;
    #pragma unroll
    for (int mt=0;mt<4;++mt)
        #pragma unroll
        for (int nt=0;nt<4;++nt){
            const int n = n0 + 64*wn + 16*nt + m15;
            const float bb = bcat[896 + n];
            #pragma unroll
            for (int reg=0;reg<4;++reg){
                const int m = row0 + 64*wm + 16*mt + q*4 + reg;
                out[(size_t)m*512 + n] = x[(size_t)m*512 + n] + acc[mt][nt][reg] + bb;
            }
        }
}

extern "C" void kernel_launch(void* const* d_in, const int* in_sizes, int n_in,
                              void* d_out, int out_size, void* d_ws, size_t ws_size,
                              hipStream_t stream) {
    const float* x    = (const float*)d_in[0];
    const float* Wk   = (const float*)d_in[1];
    const float* bk   = (const float*)d_in[2];
    const float* Wq   = (const float*)d_in[3];
    const float* bq   = (const float*)d_in[4];
    const float* Wv   = (const float*)d_in[5];
    const float* bv   = (const float*)d_in[6];
    const float* ln_g = (const float*)d_in[7];
    const float* ln_b = (const float*)d_in[8];
    const float* Wo   = (const float*)d_in[9];
    const float* bo   = (const float*)d_in[10];
    const float* set_w      = (const float*)d_in[11];
    const float* pos_phases = (const float*)d_in[12];
    const float* pos_weight = (const float*)d_in[13];
    const float* Wg1  = (const float*)d_in[14];
    const float* bg1  = (const float*)d_in[15];
    const float* Wg2  = (const float*)d_in[16];
    const float* bg2  = (const float*)d_in[17];
    float* out = (float*)d_out;

    // workspace (~13.5 MB): fp32 region then bf16 region
    float* ws   = (float*)d_ws;
    float* Yh   = ws;                                     // 2048*384 f32
    float* bcat = Yh + (size_t)2048*YH;                   // 1408 f32
    unsigned short* Wb  = (unsigned short*)(bcat + NW);   // 1408*512 bf16
    unsigned short* xb  = Wb  + (size_t)NW*512;           // 2048*512
    unsigned short* Vt  = xb  + (size_t)2048*512;         // 2*512*1024
    unsigned short* ab  = Vt  + (size_t)BB*512*1024;      // 2048*64
    unsigned short* Rb  = ab  + (size_t)2048*NCH;         // 2048*64
    unsigned short* aT  = Rb  + (size_t)2048*NCH;         // 2*64*1024
    unsigned short* Tn  = aT  + (size_t)BB*NCH*1024;      // 2048*512

    k_prep<<<dim3(NW + 2048), 128, 0, stream>>>(
        Wv,Wg1,Wk,Wq,Wo, bv,bg1,bk,bq,bo, x, Wb, bcat, xb);
    kg1<<<dim3(2048/128, 7), 256, 0, stream>>>(xb, Wb, bcat, Vt, Yh);
    k_act<<<dim3(2048/8), 256, 0, stream>>>(
        Yh, Wg2, bg2, set_w, pos_phases, pos_weight, ab, Rb, aT);
    k_scan2<<<dim3(32), 64, 0, stream>>>(ab, Rb, aT, Vt, Tn);
    k_ln<<<dim3(2048/4), 256, 0, stream>>>(Tn, ln_g, ln_b);
    kg2<<<dim3(2048/128, 4), 256, 0, stream>>>(Tn, Wb, bcat, x, out);
}

// Round 7
// 155.196 us; speedup vs baseline: 1.5153x; 1.3740x over previous
//
#include <hip/hip_runtime.h>
#include <math.h>

#define PI_F 3.14159265358979323846f
#define BB 2
#define LL 1024
#define NCH 64
#define CHUNK 32
#define NCHUNK (LL/CHUNK)
#define NW 1408          // Wb rows: 512 Wv | 256 Wg1 | 16 Wk | 16 Wq | 96 pad0 | 512 Wo

typedef __attribute__((ext_vector_type(8))) short short8;
typedef __attribute__((ext_vector_type(4))) float floatx4;
typedef const __attribute__((address_space(1))) unsigned int cgu32;
typedef __attribute__((address_space(3))) unsigned int lu32;

__device__ __forceinline__ unsigned short f2bf(float f){
    unsigned u = __float_as_uint(f);
    unsigned r = (u + 0x7fff + ((u >> 16) & 1)) >> 16;   // RNE
    return (unsigned short)r;
}

// ---- prep: weights -> bf16 Wb[n][k], bcat; x -> bf16 xb ----
__global__ __launch_bounds__(128) void k_prep(
    const float* __restrict__ Wv, const float* __restrict__ Wg1,
    const float* __restrict__ Wk, const float* __restrict__ Wq,
    const float* __restrict__ Wo,
    const float* __restrict__ bv, const float* __restrict__ bg1,
    const float* __restrict__ bk, const float* __restrict__ bq,
    const float* __restrict__ bo, const float* __restrict__ x,
    unsigned short* __restrict__ Wb, float* __restrict__ bcat,
    unsigned short* __restrict__ xb)
{
    const int bid = blockIdx.x, tid = threadIdx.x;
    if (bid < NW){
        const int n = bid;
        const float* src = (n<512) ? Wv  + (size_t)n*512
                         : (n<768) ? Wg1 + (size_t)(n-512)*512
                         : (n<784) ? Wk  + (size_t)(n-768)*512
                         : (n<800) ? Wq  + (size_t)(n-784)*512
                         : (n<896) ? (const float*)0
                                   : Wo  + (size_t)(n-896)*512;
        float4 v = make_float4(0.f,0.f,0.f,0.f);
        if (src) v = ((const float4*)src)[tid];
        ushort4 o; o.x=f2bf(v.x); o.y=f2bf(v.y); o.z=f2bf(v.z); o.w=f2bf(v.w);
        ((ushort4*)(Wb + (size_t)n*512))[tid] = o;
        if (tid == 0)
            bcat[n] = (n<512)?bv[n] : (n<768)?bg1[n-512] : (n<784)?bk[n-768]
                    : (n<800)?bq[n-784] : (n<896)?0.f : bo[n-896];
    } else {
        const size_t i = (size_t)(bid - NW)*128 + tid;    // float4 index
        float4 v = ((const float4*)x)[i];
        ushort4 o; o.x=f2bf(v.x); o.y=f2bf(v.y); o.z=f2bf(v.z); o.w=f2bf(v.w);
        ((ushort4*)xb)[i] = o;
    }
}

// ---- MFMA 128x128x512 tile core: 4 waves, each owns a 64x64 quadrant ----
__device__ __forceinline__ void gemm128(
    const unsigned short* Ag, const unsigned short* Bg,
    short* As, short* Bs, int tid, floatx4 acc[4][4])
{
    const int lane = tid & 63, w = tid >> 6;
    const int wm = w & 1, wn = w >> 1;
    const int q = lane >> 4, m15 = lane & 15;
    for (int kt = 0; kt < 512; kt += 64) {
        __syncthreads();                   // prior iter's frag reads done
        #pragma unroll
        for (int i = 0; i < 4; ++i) {
            const int rowbase = w*32 + i*8;
            const int r  = rowbase + (lane >> 3);
            const int gb = (lane & 7) ^ (r & 7);
            __builtin_amdgcn_global_load_lds(
                (cgu32*)(const void*)(Ag + (size_t)r*512 + kt + gb*8),
                (lu32*)(As + rowbase*64), 16, 0, 0);
            __builtin_amdgcn_global_load_lds(
                (cgu32*)(const void*)(Bg + (size_t)r*512 + kt + gb*8),
                (lu32*)(Bs + rowbase*64), 16, 0, 0);
        }
        __syncthreads();                   // compiler drains vmcnt here
        #pragma unroll
        for (int k32 = 0; k32 < 64; k32 += 32) {
            short8 af[4], bf[4];
            #pragma unroll
            for (int t = 0; t < 4; ++t) {
                const int ra  = 64*wm + 16*t + m15;
                const int sba = ((k32>>3) + q) ^ (ra & 7);
                af[t] = *(const short8*)(As + ra*64 + sba*8);
                const int rb  = 64*wn + 16*t + m15;
                const int sbb = ((k32>>3) + q) ^ (rb & 7);
                bf[t] = *(const short8*)(Bs + rb*64 + sbb*8);
            }
            #pragma unroll
            for (int mt = 0; mt < 4; ++mt)
                #pragma unroll
                for (int nt = 0; nt < 4; ++nt)
                    acc[mt][nt] = __builtin_amdgcn_mfma_f32_16x16x32_bf16(
                        af[mt], bf[nt], acc[mt][nt], 0, 0, 0);
        }
    }
}

// ---- kg1f: fused GEMM1.
//  blocks 0..63  : Vr 128x128 tiles -> Vt bf16 [b][d][l]
//  blocks 64..95 : act 64x288 tile (h|kp|qp) -> gate+phases epilogue -> ab/Rb/aT
__global__ __launch_bounds__(256,2) void kg1f(
    const unsigned short* __restrict__ xb, const unsigned short* __restrict__ Wb,
    const float* __restrict__ bcat, const float* __restrict__ Wg2,
    const float* __restrict__ bg2, const float* __restrict__ set_w,
    const float* __restrict__ pos_phases, const float* __restrict__ pos_weight,
    unsigned short* __restrict__ Vt,
    unsigned short* __restrict__ ab, unsigned short* __restrict__ Rb,
    unsigned short* __restrict__ aT)
{
    __shared__ short smem[22528];       // 44 KB union
    const int bid = blockIdx.x, tid = threadIdx.x;
    const int lane = tid & 63, w = tid >> 6;
    const int q = lane >> 4, m15 = lane & 15;

    if (bid < 64){
        // ---------------- Vr path (verified round 4-6) ----------------
        short* As = smem;               // 128*64
        short* Bs = smem + 128*64;      // 128*64
        const int row0 = (bid >> 2)*128, n0 = (bid & 3)*128;
        floatx4 acc[4][4];
        #pragma unroll
        for (int mt=0;mt<4;++mt)
            #pragma unroll
            for (int nt=0;nt<4;++nt) acc[mt][nt] = (floatx4){0.f,0.f,0.f,0.f};
        gemm128(xb + (size_t)row0*512, Wb + (size_t)n0*512, As, Bs, tid, acc);
        const int wm = w & 1, wn = w >> 1;
        const int b = row0 >> 10, lb = row0 & 1023;
        #pragma unroll
        for (int mt=0;mt<4;++mt)
            #pragma unroll
            for (int nt=0;nt<4;++nt){
                const int d = n0 + 64*wn + 16*nt + m15;
                const float bb = bcat[d];
                const int l0 = lb + 64*wm + 16*mt + q*4;
                ushort4 o;
                o.x = f2bf(acc[mt][nt][0] + bb);
                o.y = f2bf(acc[mt][nt][1] + bb);
                o.z = f2bf(acc[mt][nt][2] + bb);
                o.w = f2bf(acc[mt][nt][3] + bb);
                *(ushort4*)(Vt + ((size_t)(b*512 + d))*1024 + l0) = o;
            }
    } else {
        // ---------------- act path: 64 rows x 288 cols (Wb rows 512..799) ----
        short* As2 = smem;              // 64*64  (8 KB)
        short* Bs2 = smem + 64*64;      // 288*64 (36 KB)
        const int r0 = (bid - 64)*64;
        floatx4 acc2[18];
        #pragma unroll
        for (int nt=0;nt<18;++nt) acc2[nt] = (floatx4){0.f,0.f,0.f,0.f};
        for (int kt = 0; kt < 512; kt += 64){
            __syncthreads();
            #pragma unroll
            for (int i=0;i<2;++i){
                const int rowbase = (w*2 + i)*8;
                const int r = rowbase + (lane >> 3);
                const int gb = (lane & 7) ^ (r & 7);
                __builtin_amdgcn_global_load_lds(
                    (cgu32*)(const void*)(xb + (size_t)(r0 + r)*512 + kt + gb*8),
                    (lu32*)(As2 + rowbase*64), 16, 0, 0);
            }
            #pragma unroll
            for (int i=0;i<9;++i){
                const int rowbase = (w*9 + i)*8;
                const int r = rowbase + (lane >> 3);
                const int gb = (lane & 7) ^ (r & 7);
                __builtin_amdgcn_global_load_lds(
                    (cgu32*)(const void*)(Wb + (size_t)(512 + r)*512 + kt + gb*8),
                    (lu32*)(Bs2 + rowbase*64), 16, 0, 0);
            }
            __syncthreads();
            #pragma unroll
            for (int k32 = 0; k32 < 64; k32 += 32){
                const int ra  = 16*w + m15;
                const int sba = ((k32>>3) + q) ^ (ra & 7);
                short8 af = *(const short8*)(As2 + ra*64 + sba*8);
                #pragma unroll
                for (int nt=0;nt<18;++nt){
                    const int rb  = 16*nt + m15;
                    const int sbb = ((k32>>3) + q) ^ (rb & 7);
                    short8 bf = *(const short8*)(Bs2 + rb*64 + sbb*8);
                    acc2[nt] = __builtin_amdgcn_mfma_f32_16x16x32_bf16(
                        af, bf, acc2[nt], 0, 0, 0);
                }
            }
        }
        // ---- epilogue: gate + phases for rows r0+16w .. +15 ----
        float s0=set_w[0], s1=set_w[1], s2=set_w[2], s3=set_w[3];
        float mx = fmaxf(fmaxf(s0,s1), fmaxf(s2,s3));
        float e0=expf(s0-mx), e1=expf(s1-mx), e2=expf(s2-mx), e3=expf(s3-mx);
        float esum = e0+e1+e2+e3;
        float spw = 1.f/(1.f+expf(-pos_weight[0]));
        float b2 = bg2[0];
        float part[4] = {0.f,0.f,0.f,0.f};
        #pragma unroll
        for (int nt=0;nt<16;++nt){
            const float w2 = Wg2[16*nt + m15];
            const float hb = bcat[512 + 16*nt + m15];
            #pragma unroll
            for (int reg=0;reg<4;++reg){
                float hv = acc2[nt][reg] + hb;
                float ge = 0.5f*hv*(1.f + erff(hv*0.70710678118f));
                part[reg] += ge*w2;
            }
        }
        #pragma unroll
        for (int off=8; off; off>>=1)
            #pragma unroll
            for (int reg=0;reg<4;++reg) part[reg] += __shfl_xor(part[reg], off, 64);
        const int j = m15;
        const float bkj = bcat[768 + j], bqj = bcat[784 + j];
        const float wsm = (j<4?e0: j<8?e1: j<12?e2: e3) / esum;
        #pragma unroll
        for (int reg=0;reg<4;++reg){
            const int row = r0 + 16*w + q*4 + reg;
            const int l = row & (LL-1), b = row >> 10;
            float g = 1.f/(1.f+expf(-(part[reg] + b2)));
            float kang = PI_F*tanhf(acc2[16][reg] + bkj);
            float qang = PI_F*tanhf(acc2[17][reg] + bqj);
            float rnorm = 1.f/(2.f*sqrtf((float)(l+1)));
            float av[4], rv[4];
            av[0] = cosf(kang); av[1] = sinf(kang);
            float cw = g*wsm*rnorm;
            rv[0] = cw*cosf(qang); rv[1] = cw*sinf(qang);
            float ph = pos_phases[(size_t)l*16 + j];
            float pc = cosf(ph), ps = sinf(ph);
            av[2] = pc; av[3] = ps;
            float cp = (1.f-g)*spw*rnorm;
            rv[2] = cp*pc; rv[3] = cp*ps;
            unsigned short* arow = ab + (size_t)row*NCH;
            unsigned short* Rrow = Rb + (size_t)row*NCH;
            #pragma unroll
            for (int t=0;t<4;++t){
                arow[16*t + j] = f2bf(av[t]);
                Rrow[16*t + j] = f2bf(rv[t]);
                aT[((size_t)(b*NCH + 16*t + j))*1024 + l] = f2bf(av[t]);
            }
        }
    }
}

// ---- K2a (MFMA): P[b][c][d][k] = sum_{l in chunk} a[k][l] * V[l][d] ----
__global__ __launch_bounds__(256) void k2a_chunksum(
    const unsigned short* __restrict__ aT, const unsigned short* __restrict__ Vt,
    float* __restrict__ P)
{
    const int c = blockIdx.x, b = blockIdx.y, z = blockIdx.z;
    const int tid = threadIdx.x, lane = tid & 63, w = tid >> 6;
    const int q = lane >> 4, m15 = lane & 15;
    short8 af[4];
    #pragma unroll
    for (int mt=0;mt<4;++mt)
        af[mt] = *(const short8*)(aT + ((size_t)b*NCH + 16*mt + m15)*1024 + c*32 + q*8);
    floatx4 acc[4][4];
    #pragma unroll
    for (int mt=0;mt<4;++mt)
        #pragma unroll
        for (int nt=0;nt<4;++nt) acc[mt][nt] = (floatx4){0.f,0.f,0.f,0.f};
    #pragma unroll
    for (int nt=0;nt<4;++nt){
        const int d = z*256 + w*64 + 16*nt + m15;
        short8 bf = *(const short8*)(Vt + ((size_t)(b*512 + d))*1024 + c*32 + q*8);
        #pragma unroll
        for (int mt=0;mt<4;++mt)
            acc[mt][nt] = __builtin_amdgcn_mfma_f32_16x16x32_bf16(af[mt], bf, acc[mt][nt], 0,0,0);
    }
    float* Pc = P + ((size_t)(b*NCHUNK + c))*512*NCH;
    #pragma unroll
    for (int mt=0;mt<4;++mt)
        #pragma unroll
        for (int nt=0;nt<4;++nt){
            const int d = z*256 + w*64 + 16*nt + m15;
            *(floatx4*)(Pc + (size_t)d*NCH + 16*mt + q*4) = acc[mt][nt];
        }
}

// ---- K2b: exclusive prefix over chunks -> S0t bf16 ----
__global__ __launch_bounds__(256) void k2b_prefix(
    const float* __restrict__ P, unsigned short* __restrict__ S0t)
{
    const int b = blockIdx.y;
    const size_t idx = (size_t)blockIdx.x*256 + threadIdx.x;   // over 512*64
    float run = 0.f;
    for (int c=0;c<NCHUNK;++c){
        const size_t o = ((size_t)(b*NCHUNK + c))*512*NCH + idx;
        float v = P[o];
        S0t[o] = f2bf(run);
        run += v;
    }
}

// ---- K2c (MFMA): T = tril(R a^T) @ V + R @ S0, then LN -> Tn bf16 ----
__global__ __launch_bounds__(256) void k2c_scan(
    const unsigned short* __restrict__ ab, const unsigned short* __restrict__ Rb,
    const unsigned short* __restrict__ Vt, const unsigned short* __restrict__ S0t,
    const float* __restrict__ ln_g, const float* __restrict__ ln_b,
    unsigned short* __restrict__ Tn)
{
    __shared__ short Msh[32*32];
    __shared__ float Tsh[32*512];
    const int c = blockIdx.x, b = blockIdx.y;
    const int tid = threadIdx.x, lane = tid & 63, w = tid >> 6;
    const int q = lane >> 4, m15 = lane & 15;
    const int grow = b*1024 + c*32;

    if (w == 0){                       // wave 0 computes M = tril(R @ a^T)
        floatx4 mcc[2][2];
        #pragma unroll
        for (int mt=0;mt<2;++mt)
            #pragma unroll
            for (int nt=0;nt<2;++nt) mcc[mt][nt] = (floatx4){0.f,0.f,0.f,0.f};
        #pragma unroll
        for (int ks=0;ks<2;++ks){
            short8 ra[2], bb[2];
            #pragma unroll
            for (int t=0;t<2;++t){
                ra[t] = *(const short8*)(Rb + (size_t)(grow + 16*t + m15)*NCH + ks*32 + q*8);
                bb[t] = *(const short8*)(ab + (size_t)(grow + 16*t + m15)*NCH + ks*32 + q*8);
            }
            #pragma unroll
            for (int mt=0;mt<2;++mt)
                #pragma unroll
                for (int nt=0;nt<2;++nt)
                    mcc[mt][nt] = __builtin_amdgcn_mfma_f32_16x16x32_bf16(
                        ra[mt], bb[nt], mcc[mt][nt], 0,0,0);
        }
        #pragma unroll
        for (int mt=0;mt<2;++mt)
            #pragma unroll
            for (int nt=0;nt<2;++nt){
                const int nl = 16*nt + m15;
                #pragma unroll
                for (int reg=0;reg<4;++reg){
                    const int ml = 16*mt + q*4 + reg;
                    Msh[ml*32 + nl] = (nl <= ml) ? (short)f2bf(mcc[mt][nt][reg]) : (short)0;
                }
            }
    }
    __syncthreads();

    short8 a1[2], a2[2][2];
    #pragma unroll
    for (int mt=0;mt<2;++mt){
        a1[mt] = *(const short8*)(Msh + (16*mt + m15)*32 + q*8);
        #pragma unroll
        for (int ks=0;ks<2;++ks)
            a2[ks][mt] = *(const short8*)(Rb + (size_t)(grow + 16*mt + m15)*NCH + ks*32 + q*8);
    }
    floatx4 acc[2][8];
    #pragma unroll
    for (int mt=0;mt<2;++mt)
        #pragma unroll
        for (int nt=0;nt<8;++nt) acc[mt][nt] = (floatx4){0.f,0.f,0.f,0.f};
    const unsigned short* S0c = S0t + ((size_t)(b*NCHUNK + c))*512*NCH;
    #pragma unroll
    for (int nt=0;nt<8;++nt){
        const int d = w*128 + 16*nt + m15;
        short8 b1 = *(const short8*)(Vt + ((size_t)(b*512 + d))*1024 + c*32 + q*8);
        #pragma unroll
        for (int mt=0;mt<2;++mt)
            acc[mt][nt] = __builtin_amdgcn_mfma_f32_16x16x32_bf16(a1[mt], b1, acc[mt][nt], 0,0,0);
        #pragma unroll
        for (int ks=0;ks<2;++ks){
            short8 b2 = *(const short8*)(S0c + (size_t)d*NCH + ks*32 + q*8);
            #pragma unroll
            for (int mt=0;mt<2;++mt)
                acc[mt][nt] = __builtin_amdgcn_mfma_f32_16x16x32_bf16(a2[ks][mt], b2, acc[mt][nt], 0,0,0);
        }
    }
    #pragma unroll
    for (int mt=0;mt<2;++mt)
        #pragma unroll
        for (int nt=0;nt<8;++nt){
            const int d = w*128 + 16*nt + m15;
            #pragma unroll
            for (int reg=0;reg<4;++reg)
                Tsh[(16*mt + q*4 + reg)*512 + d] = acc[mt][nt][reg];
        }
    __syncthreads();

    #pragma unroll
    for (int i=0;i<8;++i){
        const int r = w*8 + i;
        float s=0.f, sq=0.f;
        #pragma unroll
        for (int t=0;t<8;++t){
            float v = Tsh[r*512 + lane + 64*t];
            s += v; sq += v*v;
        }
        #pragma unroll
        for (int off=32; off; off>>=1){
            s += __shfl_xor(s, off, 64); sq += __shfl_xor(sq, off, 64);
        }
        float mu  = s*(1.f/512.f);
        float var = sq*(1.f/512.f) - mu*mu;
        float rsd = rsqrtf(var + 1e-5f);
        unsigned short* trow = Tn + (size_t)(grow + r)*512;
        #pragma unroll
        for (int t=0;t<8;++t){
            const int d = lane + 64*t;
            float v = (Tsh[r*512 + d] - mu)*rsd*ln_g[d] + ln_b[d];
            trow[d] = f2bf(v);
        }
    }
}

// ---- GEMM2: out = x + Tn @ Wo^T + bo ----
__global__ __launch_bounds__(256) void kg2(
    const unsigned short* __restrict__ Tn, const unsigned short* __restrict__ Wb,
    const float* __restrict__ bcat, const float* __restrict__ x,
    float* __restrict__ out)
{
    __shared__ short As[128*64], Bs[128*64];
    const int tid = threadIdx.x;
    const int row0 = blockIdx.x*128, n0 = blockIdx.y*128;
    floatx4 acc[4][4];
    #pragma unroll
    for (int mt=0;mt<4;++mt)
        #pragma unroll
        for (int nt=0;nt<4;++nt) acc[mt][nt] = (floatx4){0.f,0.f,0.f,0.f};
    gemm128(Tn + (size_t)row0*512, Wb + (size_t)(896+n0)*512, As, Bs, tid, acc);
    const int lane = tid & 63, w = tid >> 6;
    const int wm = w & 1, wn = w >> 1, q = lane >> 4, m15 = lane & 15;
    #pragma unroll
    for (int mt=0;mt<4;++mt)
        #pragma unroll
        for (int nt=0;nt<4;++nt){
            const int n = n0 + 64*wn + 16*nt + m15;
            const float bb = bcat[896 + n];
            #pragma unroll
            for (int reg=0;reg<4;++reg){
                const int m = row0 + 64*wm + 16*mt + q*4 + reg;
                out[(size_t)m*512 + n] = x[(size_t)m*512 + n] + acc[mt][nt][reg] + bb;
            }
        }
}

extern "C" void kernel_launch(void* const* d_in, const int* in_sizes, int n_in,
                              void* d_out, int out_size, void* d_ws, size_t ws_size,
                              hipStream_t stream) {
    const float* x    = (const float*)d_in[0];
    const float* Wk   = (const float*)d_in[1];
    const float* bk   = (const float*)d_in[2];
    const float* Wq   = (const float*)d_in[3];
    const float* bq   = (const float*)d_in[4];
    const float* Wv   = (const float*)d_in[5];
    const float* bv   = (const float*)d_in[6];
    const float* ln_g = (const float*)d_in[7];
    const float* ln_b = (const float*)d_in[8];
    const float* Wo   = (const float*)d_in[9];
    const float* bo   = (const float*)d_in[10];
    const float* set_w      = (const float*)d_in[11];
    const float* pos_phases = (const float*)d_in[12];
    const float* pos_weight = (const float*)d_in[13];
    const float* Wg1  = (const float*)d_in[14];
    const float* bg1  = (const float*)d_in[15];
    const float* Wg2  = (const float*)d_in[16];
    const float* bg2  = (const float*)d_in[17];
    float* out = (float*)d_out;

    // workspace (~33 MB): fp32 region then bf16 region
    float* ws   = (float*)d_ws;
    float* bcat = ws;                                     // 1408 f32
    float* P    = bcat + NW;                              // 2*32*512*64 f32
    unsigned short* Wb  = (unsigned short*)(P + (size_t)BB*NCHUNK*512*NCH);
    unsigned short* xb  = Wb  + (size_t)NW*512;           // 2048*512
    unsigned short* Vt  = xb  + (size_t)2048*512;         // 2*512*1024
    unsigned short* ab  = Vt  + (size_t)BB*512*1024;      // 2048*64
    unsigned short* Rb  = ab  + (size_t)2048*NCH;         // 2048*64
    unsigned short* aT  = Rb  + (size_t)2048*NCH;         // 2*64*1024
    unsigned short* S0t = aT  + (size_t)BB*NCH*1024;      // 2*32*512*64
    unsigned short* Tn  = S0t + (size_t)BB*NCHUNK*512*NCH;// 2048*512

    k_prep<<<dim3(NW + 2048), 128, 0, stream>>>(
        Wv,Wg1,Wk,Wq,Wo, bv,bg1,bk,bq,bo, x, Wb, bcat, xb);
    kg1f<<<dim3(96), 256, 0, stream>>>(
        xb, Wb, bcat, Wg2, bg2, set_w, pos_phases, pos_weight, Vt, ab, Rb, aT);
    k2a_chunksum<<<dim3(NCHUNK, BB, 2), 256, 0, stream>>>(aT, Vt, P);
    k2b_prefix<<<dim3(512*NCH/256, BB), 256, 0, stream>>>(P, S0t);
    k2c_scan<<<dim3(NCHUNK, BB), 256, 0, stream>>>(ab, Rb, Vt, S0t, ln_g, ln_b, Tn);
    kg2<<<dim3(2048/128, 4), 256, 0, stream>>>(Tn, Wb, bcat, x, out);
}

// Round 8
// 148.517 us; speedup vs baseline: 1.5834x; 1.0450x over previous
//
#include <hip/hip_runtime.h>
#include <math.h>

#define PI_F 3.14159265358979323846f
#define BB 2
#define LL 1024
#define NCH 64
#define CHUNK 32
#define NCHUNK (LL/CHUNK)
#define NW 1408          // Wb rows: 512 Wv | 256 Wg1 | 16 Wk | 16 Wq | 96 pad0 | 512 Wo

typedef __attribute__((ext_vector_type(8))) short short8;
typedef __attribute__((ext_vector_type(4))) float floatx4;
typedef const __attribute__((address_space(1))) unsigned int cgu32;
typedef __attribute__((address_space(3))) unsigned int lu32;

__device__ __forceinline__ unsigned short f2bf(float f){
    unsigned u = __float_as_uint(f);
    unsigned r = (u + 0x7fff + ((u >> 16) & 1)) >> 16;   // RNE
    return (unsigned short)r;
}

// ---- prep: weights -> bf16 Wb[n][k], bcat; x -> bf16 xb ----
__global__ __launch_bounds__(128) void k_prep(
    const float* __restrict__ Wv, const float* __restrict__ Wg1,
    const float* __restrict__ Wk, const float* __restrict__ Wq,
    const float* __restrict__ Wo,
    const float* __restrict__ bv, const float* __restrict__ bg1,
    const float* __restrict__ bk, const float* __restrict__ bq,
    const float* __restrict__ bo, const float* __restrict__ x,
    unsigned short* __restrict__ Wb, float* __restrict__ bcat,
    unsigned short* __restrict__ xb)
{
    const int bid = blockIdx.x, tid = threadIdx.x;
    if (bid < NW){
        const int n = bid;
        const float* src = (n<512) ? Wv  + (size_t)n*512
                         : (n<768) ? Wg1 + (size_t)(n-512)*512
                         : (n<784) ? Wk  + (size_t)(n-768)*512
                         : (n<800) ? Wq  + (size_t)(n-784)*512
                         : (n<896) ? (const float*)0
                                   : Wo  + (size_t)(n-896)*512;
        float4 v = make_float4(0.f,0.f,0.f,0.f);
        if (src) v = ((const float4*)src)[tid];
        ushort4 o; o.x=f2bf(v.x); o.y=f2bf(v.y); o.z=f2bf(v.z); o.w=f2bf(v.w);
        ((ushort4*)(Wb + (size_t)n*512))[tid] = o;
        if (tid == 0)
            bcat[n] = (n<512)?bv[n] : (n<768)?bg1[n-512] : (n<784)?bk[n-768]
                    : (n<800)?bq[n-784] : (n<896)?0.f : bo[n-896];
    } else {
        const size_t i = (size_t)(bid - NW)*128 + tid;    // float4 index
        float4 v = ((const float4*)x)[i];
        ushort4 o; o.x=f2bf(v.x); o.y=f2bf(v.y); o.z=f2bf(v.z); o.w=f2bf(v.w);
        ((ushort4*)xb)[i] = o;
    }
}

// ---- MFMA 64x64x512 tile core (verified rounds 3-4): 4 waves, 2x2 16-frag ----
__device__ __forceinline__ void gemm64x64(
    const unsigned short* Ag, const unsigned short* Bg,
    short* As, short* Bs, int tid, floatx4 acc[2][2])
{
    const int lane = tid & 63, w = tid >> 6;
    const int wm = w & 1, wn = w >> 1;
    const int q = lane >> 4, m15 = lane & 15;
    for (int kt = 0; kt < 512; kt += 64) {
        __syncthreads();
        #pragma unroll
        for (int i = 0; i < 2; ++i) {
            const int rowbase = (w*2 + i) * 8;
            const int r  = rowbase + (lane >> 3);
            const int gb = (lane & 7) ^ (r & 7);
            __builtin_amdgcn_global_load_lds(
                (cgu32*)(const void*)(Ag + (size_t)r*512 + kt + gb*8),
                (lu32*)(As + rowbase*64), 16, 0, 0);
            __builtin_amdgcn_global_load_lds(
                (cgu32*)(const void*)(Bg + (size_t)r*512 + kt + gb*8),
                (lu32*)(Bs + rowbase*64), 16, 0, 0);
        }
        __syncthreads();
        #pragma unroll
        for (int k32 = 0; k32 < 64; k32 += 32) {
            short8 af[2], bf[2];
            #pragma unroll
            for (int t = 0; t < 2; ++t) {
                const int ra  = 32*wm + 16*t + m15;
                const int sba = ((k32>>3) + q) ^ (ra & 7);
                af[t] = *(const short8*)(As + ra*64 + sba*8);
                const int rb  = 32*wn + 16*t + m15;
                const int sbb = ((k32>>3) + q) ^ (rb & 7);
                bf[t] = *(const short8*)(Bs + rb*64 + sbb*8);
            }
            #pragma unroll
            for (int mt = 0; mt < 2; ++mt)
                #pragma unroll
                for (int nt = 0; nt < 2; ++nt)
                    acc[mt][nt] = __builtin_amdgcn_mfma_f32_16x16x32_bf16(
                        af[mt], bf[nt], acc[mt][nt], 0, 0, 0);
        }
    }
}

// ---- kg1f: fused GEMM1.
//  blocks 0..255  : Vr 64x64 tiles -> Vt bf16 [b][d][l]   (row=(bid>>3)*64, n=(bid&7)*64)
//  blocks 256..287: act 64x288 tile (h|kp|qp) -> gate+phases epilogue -> ab/Rb/aT
__global__ __launch_bounds__(256,2) void kg1f(
    const unsigned short* __restrict__ xb, const unsigned short* __restrict__ Wb,
    const float* __restrict__ bcat, const float* __restrict__ Wg2,
    const float* __restrict__ bg2, const float* __restrict__ set_w,
    const float* __restrict__ pos_phases, const float* __restrict__ pos_weight,
    unsigned short* __restrict__ Vt,
    unsigned short* __restrict__ ab, unsigned short* __restrict__ Rb,
    unsigned short* __restrict__ aT)
{
    __shared__ short smem[22528];       // 44 KB union (act path); Vr path uses 16 KB
    const int bid = blockIdx.x, tid = threadIdx.x;
    const int lane = tid & 63, w = tid >> 6;
    const int q = lane >> 4, m15 = lane & 15;

    if (bid < 256){
        // ---------------- Vr path: 64x64 tiles (verified round 3/4) ----------
        short* As = smem;               // 64*64
        short* Bs = smem + 64*64;
        const int row0 = (bid >> 3)*64, n0 = (bid & 7)*64;
        floatx4 acc[2][2];
        #pragma unroll
        for (int mt=0;mt<2;++mt)
            #pragma unroll
            for (int nt=0;nt<2;++nt) acc[mt][nt] = (floatx4){0.f,0.f,0.f,0.f};
        gemm64x64(xb + (size_t)row0*512, Wb + (size_t)n0*512, As, Bs, tid, acc);
        const int wm = w & 1, wn = w >> 1;
        const int b = row0 >> 10, lb = row0 & 1023;
        #pragma unroll
        for (int mt=0;mt<2;++mt)
            #pragma unroll
            for (int nt=0;nt<2;++nt){
                const int d = n0 + 32*wn + 16*nt + m15;
                const float bb = bcat[d];
                const int l0 = lb + 32*wm + 16*mt + q*4;
                ushort4 o;
                o.x = f2bf(acc[mt][nt][0] + bb);
                o.y = f2bf(acc[mt][nt][1] + bb);
                o.z = f2bf(acc[mt][nt][2] + bb);
                o.w = f2bf(acc[mt][nt][3] + bb);
                *(ushort4*)(Vt + ((size_t)(b*512 + d))*1024 + l0) = o;
            }
    } else {
        // ---------------- act path: 64 rows x 288 cols (verified round 7) ----
        short* As2 = smem;              // 64*64  (8 KB)
        short* Bs2 = smem + 64*64;      // 288*64 (36 KB)
        const int r0 = (bid - 256)*64;
        floatx4 acc2[18];
        #pragma unroll
        for (int nt=0;nt<18;++nt) acc2[nt] = (floatx4){0.f,0.f,0.f,0.f};
        for (int kt = 0; kt < 512; kt += 64){
            __syncthreads();
            #pragma unroll
            for (int i=0;i<2;++i){
                const int rowbase = (w*2 + i)*8;
                const int r = rowbase + (lane >> 3);
                const int gb = (lane & 7) ^ (r & 7);
                __builtin_amdgcn_global_load_lds(
                    (cgu32*)(const void*)(xb + (size_t)(r0 + r)*512 + kt + gb*8),
                    (lu32*)(As2 + rowbase*64), 16, 0, 0);
            }
            #pragma unroll
            for (int i=0;i<9;++i){
                const int rowbase = (w*9 + i)*8;
                const int r = rowbase + (lane >> 3);
                const int gb = (lane & 7) ^ (r & 7);
                __builtin_amdgcn_global_load_lds(
                    (cgu32*)(const void*)(Wb + (size_t)(512 + r)*512 + kt + gb*8),
                    (lu32*)(Bs2 + rowbase*64), 16, 0, 0);
            }
            __syncthreads();
            #pragma unroll
            for (int k32 = 0; k32 < 64; k32 += 32){
                const int ra  = 16*w + m15;
                const int sba = ((k32>>3) + q) ^ (ra & 7);
                short8 af = *(const short8*)(As2 + ra*64 + sba*8);
                #pragma unroll
                for (int nt=0;nt<18;++nt){
                    const int rb  = 16*nt + m15;
                    const int sbb = ((k32>>3) + q) ^ (rb & 7);
                    short8 bf = *(const short8*)(Bs2 + rb*64 + sbb*8);
                    acc2[nt] = __builtin_amdgcn_mfma_f32_16x16x32_bf16(
                        af, bf, acc2[nt], 0, 0, 0);
                }
            }
        }
        // ---- epilogue: gate + phases for rows r0+16w .. +15 ----
        float s0=set_w[0], s1=set_w[1], s2=set_w[2], s3=set_w[3];
        float mx = fmaxf(fmaxf(s0,s1), fmaxf(s2,s3));
        float e0=expf(s0-mx), e1=expf(s1-mx), e2=expf(s2-mx), e3=expf(s3-mx);
        float esum = e0+e1+e2+e3;
        float spw = 1.f/(1.f+expf(-pos_weight[0]));
        float b2 = bg2[0];
        float part[4] = {0.f,0.f,0.f,0.f};
        #pragma unroll
        for (int nt=0;nt<16;++nt){
            const float w2 = Wg2[16*nt + m15];
            const float hb = bcat[512 + 16*nt + m15];
            #pragma unroll
            for (int reg=0;reg<4;++reg){
                float hv = acc2[nt][reg] + hb;
                float ge = 0.5f*hv*(1.f + erff(hv*0.70710678118f));
                part[reg] += ge*w2;
            }
        }
        #pragma unroll
        for (int off=8; off; off>>=1)
            #pragma unroll
            for (int reg=0;reg<4;++reg) part[reg] += __shfl_xor(part[reg], off, 64);
        const int j = m15;
        const float bkj = bcat[768 + j], bqj = bcat[784 + j];
        const float wsm = (j<4?e0: j<8?e1: j<12?e2: e3) / esum;
        #pragma unroll
        for (int reg=0;reg<4;++reg){
            const int row = r0 + 16*w + q*4 + reg;
            const int l = row & (LL-1), b = row >> 10;
            float g = 1.f/(1.f+expf(-(part[reg] + b2)));
            float kang = PI_F*tanhf(acc2[16][reg] + bkj);
            float qang = PI_F*tanhf(acc2[17][reg] + bqj);
            float rnorm = 1.f/(2.f*sqrtf((float)(l+1)));
            float av[4], rv[4];
            av[0] = cosf(kang); av[1] = sinf(kang);
            float cw = g*wsm*rnorm;
            rv[0] = cw*cosf(qang); rv[1] = cw*sinf(qang);
            float ph = pos_phases[(size_t)l*16 + j];
            float pc = cosf(ph), ps = sinf(ph);
            av[2] = pc; av[3] = ps;
            float cp = (1.f-g)*spw*rnorm;
            rv[2] = cp*pc; rv[3] = cp*ps;
            unsigned short* arow = ab + (size_t)row*NCH;
            unsigned short* Rrow = Rb + (size_t)row*NCH;
            #pragma unroll
            for (int t=0;t<4;++t){
                arow[16*t + j] = f2bf(av[t]);
                Rrow[16*t + j] = f2bf(rv[t]);
                aT[((size_t)(b*NCH + 16*t + j))*1024 + l] = f2bf(av[t]);
            }
        }
    }
}

// ---- K2a (MFMA): P[b][c][d][k] = sum_{l in chunk} a[k][l] * V[l][d] ----
__global__ __launch_bounds__(256) void k2a_chunksum(
    const unsigned short* __restrict__ aT, const unsigned short* __restrict__ Vt,
    float* __restrict__ P)
{
    const int c = blockIdx.x, b = blockIdx.y, z = blockIdx.z;
    const int tid = threadIdx.x, lane = tid & 63, w = tid >> 6;
    const int q = lane >> 4, m15 = lane & 15;
    short8 af[4];
    #pragma unroll
    for (int mt=0;mt<4;++mt)
        af[mt] = *(const short8*)(aT + ((size_t)b*NCH + 16*mt + m15)*1024 + c*32 + q*8);
    floatx4 acc[4][4];
    #pragma unroll
    for (int mt=0;mt<4;++mt)
        #pragma unroll
        for (int nt=0;nt<4;++nt) acc[mt][nt] = (floatx4){0.f,0.f,0.f,0.f};
    #pragma unroll
    for (int nt=0;nt<4;++nt){
        const int d = z*256 + w*64 + 16*nt + m15;
        short8 bf = *(const short8*)(Vt + ((size_t)(b*512 + d))*1024 + c*32 + q*8);
        #pragma unroll
        for (int mt=0;mt<4;++mt)
            acc[mt][nt] = __builtin_amdgcn_mfma_f32_16x16x32_bf16(af[mt], bf, acc[mt][nt], 0,0,0);
    }
    float* Pc = P + ((size_t)(b*NCHUNK + c))*512*NCH;
    #pragma unroll
    for (int mt=0;mt<4;++mt)
        #pragma unroll
        for (int nt=0;nt<4;++nt){
            const int d = z*256 + w*64 + 16*nt + m15;
            *(floatx4*)(Pc + (size_t)d*NCH + 16*mt + q*4) = acc[mt][nt];
        }
}

// ---- K2b: exclusive prefix over chunks -> S0t bf16 ----
__global__ __launch_bounds__(256) void k2b_prefix(
    const float* __restrict__ P, unsigned short* __restrict__ S0t)
{
    const int b = blockIdx.y;
    const size_t idx = (size_t)blockIdx.x*256 + threadIdx.x;   // over 512*64
    float run = 0.f;
    for (int c=0;c<NCHUNK;++c){
        const size_t o = ((size_t)(b*NCHUNK + c))*512*NCH + idx;
        float v = P[o];
        S0t[o] = f2bf(run);
        run += v;
    }
}

// ---- K2c (MFMA): T = tril(R a^T) @ V + R @ S0, then LN -> Tn bf16 ----
__global__ __launch_bounds__(256) void k2c_scan(
    const unsigned short* __restrict__ ab, const unsigned short* __restrict__ Rb,
    const unsigned short* __restrict__ Vt, const unsigned short* __restrict__ S0t,
    const float* __restrict__ ln_g, const float* __restrict__ ln_b,
    unsigned short* __restrict__ Tn)
{
    __shared__ short Msh[32*32];
    __shared__ float Tsh[32*512];
    const int c = blockIdx.x, b = blockIdx.y;
    const int tid = threadIdx.x, lane = tid & 63, w = tid >> 6;
    const int q = lane >> 4, m15 = lane & 15;
    const int grow = b*1024 + c*32;

    if (w == 0){                       // wave 0 computes M = tril(R @ a^T)
        floatx4 mcc[2][2];
        #pragma unroll
        for (int mt=0;mt<2;++mt)
            #pragma unroll
            for (int nt=0;nt<2;++nt) mcc[mt][nt] = (floatx4){0.f,0.f,0.f,0.f};
        #pragma unroll
        for (int ks=0;ks<2;++ks){
            short8 ra[2], bb[2];
            #pragma unroll
            for (int t=0;t<2;++t){
                ra[t] = *(const short8*)(Rb + (size_t)(grow + 16*t + m15)*NCH + ks*32 + q*8);
                bb[t] = *(const short8*)(ab + (size_t)(grow + 16*t + m15)*NCH + ks*32 + q*8);
            }
            #pragma unroll
            for (int mt=0;mt<2;++mt)
                #pragma unroll
                for (int nt=0;nt<2;++nt)
                    mcc[mt][nt] = __builtin_amdgcn_mfma_f32_16x16x32_bf16(
                        ra[mt], bb[nt], mcc[mt][nt], 0,0,0);
        }
        #pragma unroll
        for (int mt=0;mt<2;++mt)
            #pragma unroll
            for (int nt=0;nt<2;++nt){
                const int nl = 16*nt + m15;
                #pragma unroll
                for (int reg=0;reg<4;++reg){
                    const int ml = 16*mt + q*4 + reg;
                    Msh[ml*32 + nl] = (nl <= ml) ? (short)f2bf(mcc[mt][nt][reg]) : (short)0;
                }
            }
    }
    __syncthreads();

    short8 a1[2], a2[2][2];
    #pragma unroll
    for (int mt=0;mt<2;++mt){
        a1[mt] = *(const short8*)(Msh + (16*mt + m15)*32 + q*8);
        #pragma unroll
        for (int ks=0;ks<2;++ks)
            a2[ks][mt] = *(const short8*)(Rb + (size_t)(grow + 16*mt + m15)*NCH + ks*32 + q*8);
    }
    floatx4 acc[2][8];
    #pragma unroll
    for (int mt=0;mt<2;++mt)
        #pragma unroll
        for (int nt=0;nt<8;++nt) acc[mt][nt] = (floatx4){0.f,0.f,0.f,0.f};
    const unsigned short* S0c = S0t + ((size_t)(b*NCHUNK + c))*512*NCH;
    #pragma unroll
    for (int nt=0;nt<8;++nt){
        const int d = w*128 + 16*nt + m15;
        short8 b1 = *(const short8*)(Vt + ((size_t)(b*512 + d))*1024 + c*32 + q*8);
        #pragma unroll
        for (int mt=0;mt<2;++mt)
            acc[mt][nt] = __builtin_amdgcn_mfma_f32_16x16x32_bf16(a1[mt], b1, acc[mt][nt], 0,0,0);
        #pragma unroll
        for (int ks=0;ks<2;++ks){
            short8 b2 = *(const short8*)(S0c + (size_t)d*NCH + ks*32 + q*8);
            #pragma unroll
            for (int mt=0;mt<2;++mt)
                acc[mt][nt] = __builtin_amdgcn_mfma_f32_16x16x32_bf16(a2[ks][mt], b2, acc[mt][nt], 0,0,0);
        }
    }
    #pragma unroll
    for (int mt=0;mt<2;++mt)
        #pragma unroll
        for (int nt=0;nt<8;++nt){
            const int d = w*128 + 16*nt + m15;
            #pragma unroll
            for (int reg=0;reg<4;++reg)
                Tsh[(16*mt + q*4 + reg)*512 + d] = acc[mt][nt][reg];
        }
    __syncthreads();

    #pragma unroll
    for (int i=0;i<8;++i){
        const int r = w*8 + i;
        float s=0.f, sq=0.f;
        #pragma unroll
        for (int t=0;t<8;++t){
            float v = Tsh[r*512 + lane + 64*t];
            s += v; sq += v*v;
        }
        #pragma unroll
        for (int off=32; off; off>>=1){
            s += __shfl_xor(s, off, 64); sq += __shfl_xor(sq, off, 64);
        }
        float mu  = s*(1.f/512.f);
        float var = sq*(1.f/512.f) - mu*mu;
        float rsd = rsqrtf(var + 1e-5f);
        unsigned short* trow = Tn + (size_t)(grow + r)*512;
        #pragma unroll
        for (int t=0;t<8;++t){
            const int d = lane + 64*t;
            float v = (Tsh[r*512 + d] - mu)*rsd*ln_g[d] + ln_b[d];
            trow[d] = f2bf(v);
        }
    }
}

// ---- GEMM2: out = x + Tn @ Wo^T + bo (64x64 tiles, 256 blocks) ----
__global__ __launch_bounds__(256) void kg2(
    const unsigned short* __restrict__ Tn, const unsigned short* __restrict__ Wb,
    const float* __restrict__ bcat, const float* __restrict__ x,
    float* __restrict__ out)
{
    __shared__ short As[64*64], Bs[64*64];
    const int tid = threadIdx.x;
    const int row0 = blockIdx.x*64, n0 = blockIdx.y*64;
    floatx4 acc[2][2];
    #pragma unroll
    for (int mt=0;mt<2;++mt)
        #pragma unroll
        for (int nt=0;nt<2;++nt) acc[mt][nt] = (floatx4){0.f,0.f,0.f,0.f};
    gemm64x64(Tn + (size_t)row0*512, Wb + (size_t)(896+n0)*512, As, Bs, tid, acc);
    const int lane = tid & 63, w = tid >> 6;
    const int wm = w & 1, wn = w >> 1, q = lane >> 4, m15 = lane & 15;
    #pragma unroll
    for (int mt=0;mt<2;++mt)
        #pragma unroll
        for (int nt=0;nt<2;++nt){
            const int n = n0 + 32*wn + 16*nt + m15;
            const float bb = bcat[896 + n];
            #pragma unroll
            for (int reg=0;reg<4;++reg){
                const int m = row0 + 32*wm + 16*mt + q*4 + reg;
                out[(size_t)m*512 + n] = x[(size_t)m*512 + n] + acc[mt][nt][reg] + bb;
            }
        }
}

extern "C" void kernel_launch(void* const* d_in, const int* in_sizes, int n_in,
                              void* d_out, int out_size, void* d_ws, size_t ws_size,
                              hipStream_t stream) {
    const float* x    = (const float*)d_in[0];
    const float* Wk   = (const float*)d_in[1];
    const float* bk   = (const float*)d_in[2];
    const float* Wq   = (const float*)d_in[3];
    const float* bq   = (const float*)d_in[4];
    const float* Wv   = (const float*)d_in[5];
    const float* bv   = (const float*)d_in[6];
    const float* ln_g = (const float*)d_in[7];
    const float* ln_b = (const float*)d_in[8];
    const float* Wo   = (const float*)d_in[9];
    const float* bo   = (const float*)d_in[10];
    const float* set_w      = (const float*)d_in[11];
    const float* pos_phases = (const float*)d_in[12];
    const float* pos_weight = (const float*)d_in[13];
    const float* Wg1  = (const float*)d_in[14];
    const float* bg1  = (const float*)d_in[15];
    const float* Wg2  = (const float*)d_in[16];
    const float* bg2  = (const float*)d_in[17];
    float* out = (float*)d_out;

    // workspace (~33 MB): fp32 region then bf16 region
    float* ws   = (float*)d_ws;
    float* bcat = ws;                                     // 1408 f32
    float* P    = bcat + NW;                              // 2*32*512*64 f32
    unsigned short* Wb  = (unsigned short*)(P + (size_t)BB*NCHUNK*512*NCH);
    unsigned short* xb  = Wb  + (size_t)NW*512;           // 2048*512
    unsigned short* Vt  = xb  + (size_t)2048*512;         // 2*512*1024
    unsigned short* ab  = Vt  + (size_t)BB*512*1024;      // 2048*64
    unsigned short* Rb  = ab  + (size_t)2048*NCH;         // 2048*64
    unsigned short* aT  = Rb  + (size_t)2048*NCH;         // 2*64*1024
    unsigned short* S0t = aT  + (size_t)BB*NCH*1024;      // 2*32*512*64
    unsigned short* Tn  = S0t + (size_t)BB*NCHUNK*512*NCH;// 2048*512

    k_prep<<<dim3(NW + 2048), 128, 0, stream>>>(
        Wv,Wg1,Wk,Wq,Wo, bv,bg1,bk,bq,bo, x, Wb, bcat, xb);
    kg1f<<<dim3(288), 256, 0, stream>>>(
        xb, Wb, bcat, Wg2, bg2, set_w, pos_phases, pos_weight, Vt, ab, Rb, aT);
    k2a_chunksum<<<dim3(NCHUNK, BB, 2), 256, 0, stream>>>(aT, Vt, P);
    k2b_prefix<<<dim3(512*NCH/256, BB), 256, 0, stream>>>(P, S0t);
    k2c_scan<<<dim3(NCHUNK, BB), 256, 0, stream>>>(ab, Rb, Vt, S0t, ln_g, ln_b, Tn);
    kg2<<<dim3(2048/64, 512/64), 256, 0, stream>>>(Tn, Wb, bcat, x, out);
}